// Round 21
// baseline (87.096 us; speedup 1.0000x reference)
//
#include <hip/hip_runtime.h>
#include <hip/hip_bf16.h>

#define NN 65536
#define EE 524288
#define BB 256
#define LL 64
#define HH 128
#define DD2 256
#define NEF 1024

typedef __attribute__((ext_vector_type(4))) float f32x4;
typedef __attribute__((ext_vector_type(8))) __bf16 bf16x8;

__device__ __forceinline__ void gload_lds16(const void* g, void* l) {
  __builtin_amdgcn_global_load_lds(
      (__attribute__((address_space(1))) void*)(g),
      (__attribute__((address_space(3))) void*)(l), 16, 0, 0);
}

// K1 v3: latency-optimized z-path, 3 role-blocks per z-row.
// role 0: Zt; role 1: ZN; role 2: Zb + heads. 4-acc ILP everywhere.
// Blocks 768..895: W_nep->Bp; 896..911: W_nd1->Bp2.
__global__ __launch_bounds__(256) void k1_prep(
    const float* __restrict__ z, const float* __restrict__ lattice,
    const float* __restrict__ W_lat, const float* __restrict__ b_lat,
    const float* __restrict__ W_en1, const float* __restrict__ b_en1,
    const float* __restrict__ W_en2, const float* __restrict__ b_en2,
    const float* __restrict__ W_st1, const float* __restrict__ b_st1,
    const float* __restrict__ W_st2, const float* __restrict__ b_st2,
    const float* __restrict__ W_nep, const float* __restrict__ W_nd1,
    const float* __restrict__ W_ed1,
    float* __restrict__ Zt, float* __restrict__ Zb, float* __restrict__ ZN,
    __bf16* __restrict__ Bp, __bf16* __restrict__ Bp2,
    float* __restrict__ out_en, float* __restrict__ out_st)
{
  int bid = blockIdx.x, t = threadIdx.x;
  if (bid < 768) {
    int b = bid & 255, role = bid >> 8;    // roles 0,1,2
    __shared__ float zl[70];
    __shared__ float zp[DD2];
    __shared__ float red[256];
    __shared__ float hh[DD2];              // role 2 only

    if (t < LL) zl[t] = z[b*LL + t];
    else if (t < 70) zl[t] = lattice[t - LL];
    __syncthreads();

    // layer 1: zp[t], 4-acc ILP (chain 16); role 2 co-issues heads layer 1
    {
      float q0 = b_lat[t], q1 = 0.f, q2 = 0.f, q3 = 0.f;
      #pragma unroll 16
      for (int k = 0; k < LL; k += 4) {
        q0 = fmaf(zl[k],   W_lat[k*DD2 + t],     q0);
        q1 = fmaf(zl[k+1], W_lat[(k+1)*DD2 + t], q1);
        q2 = fmaf(zl[k+2], W_lat[(k+2)*DD2 + t], q2);
        q3 = fmaf(zl[k+3], W_lat[(k+3)*DD2 + t], q3);
      }
      zp[t] = fmaxf((q0 + q1) + (q2 + q3), 0.f);
    }
    if (role == 2) {
      const float* Wh = (t < HH) ? (W_en1 + t) : (W_st1 + (t - HH));
      float h0 = (t < HH) ? b_en1[t] : b_st1[t - HH];
      float h1 = 0.f;
      #pragma unroll 8
      for (int k = 0; k < 70; k += 2) {
        h0 = fmaf(zl[k],   Wh[(size_t)k*HH],     h0);
        h1 = fmaf(zl[k+1], Wh[(size_t)(k+1)*HH], h1);
      }
      hh[t] = fmaxf(h0 + h1, 0.f);
    }
    __syncthreads();

    // layer 2: 128 cols x K-split-2, 4-acc ILP (chain 32)
    {
      int col = t & 127, kh = t >> 7, k0 = kh*128;
      const float* W = (role == 0) ? (W_ed1 + col)
                     : (role == 1) ? (W_nd1 + col)
                                   : (W_ed1 + (size_t)DD2*HH + col);
      float a0=0.f, a1=0.f, a2=0.f, a3=0.f;
      #pragma unroll 8
      for (int k = k0; k < k0 + 128; k += 4) {
        a0 = fmaf(zp[k],   W[(size_t)k*HH],     a0);
        a1 = fmaf(zp[k+1], W[(size_t)(k+1)*HH], a1);
        a2 = fmaf(zp[k+2], W[(size_t)(k+2)*HH], a2);
        a3 = fmaf(zp[k+3], W[(size_t)(k+3)*HH], a3);
      }
      red[t] = (a0 + a1) + (a2 + a3);
    }
    __syncthreads();
    if (t < 128) {
      float v = red[t] + red[t + 128];
      if (role == 0)      Zt[b*HH + t] = v;
      else if (role == 1) ZN[b*HH + t] = v;
      else                Zb[b*HH + t] = v;
    }
    if (role == 2) {
      // heads layer 2: 16-lane groups, 11 outputs
      int g = t >> 4, l = t & 15;
      if (g < 11) {
        float s = 0.f;
        if (g < 2) {
          #pragma unroll
          for (int q = 0; q < 8; ++q) { int k = l + q*16; s = fmaf(hh[k], W_en2[k*2 + g], s); }
        } else {
          int j = g - 2;
          #pragma unroll
          for (int q = 0; q < 8; ++q) { int k = l + q*16; s = fmaf(hh[HH + k], W_st2[k*9 + j], s); }
        }
        s += __shfl_xor(s, 1, 64);
        s += __shfl_xor(s, 2, 64);
        s += __shfl_xor(s, 4, 64);
        s += __shfl_xor(s, 8, 64);
        if (l == 0) {
          if (g < 2) out_en[b*2 + g] = s + b_en2[g];
          else       out_st[b*9 + (g - 2)] = s + b_st2[g - 2];
        }
      }
    }
  } else if (bid < 768 + 128) {        // W_nep (1024x256) -> Bp
    int kb = bid - 768;
    int col = t;
    bf16x8 v;
    #pragma unroll
    for (int j = 0; j < 8; ++j)
      v[j] = (__bf16)W_nep[(kb*8 + j)*256 + col];
    *(bf16x8*)(Bp + (kb*256 + col)*8) = v;
  } else {                             // W_nd1 (256x128) -> Bp2
    int kb = (bid - 768 - 128)*2 + (t >> 7);
    int col = t & 127;
    bf16x8 v;
    #pragma unroll
    for (int j = 0; j < 8; ++j)
      v[j] = (__bf16)W_nd1[(kb*8 + j)*128 + col];
    *(bf16x8*)(Bp2 + (kb*128 + col)*8) = v;
  }
}

// K3: R[gs][gd][c] = relu(Zt[gs]+Zb[gd]+b_ed1) @ W_ed2 + b_ed2   (256x256x3 table)
__global__ __launch_bounds__(256) void k3_rtab(
    const float* __restrict__ Zt, const float* __restrict__ Zb,
    const float* __restrict__ b_ed1, const float* __restrict__ W_ed2,
    const float* __restrict__ b_ed2, float* __restrict__ R)
{
  __shared__ float zt_s[HH];
  __shared__ float b1_s[HH];
  __shared__ float w2_s[HH*3];
  int gs = blockIdx.x, gd = threadIdx.x;
  if (gd < HH) {
    zt_s[gd] = Zt[gs*HH + gd];
    b1_s[gd] = b_ed1[gd];
    w2_s[gd] = W_ed2[gd];
    w2_s[gd + HH] = W_ed2[gd + HH];
    w2_s[gd + 2*HH] = W_ed2[gd + 2*HH];
  }
  __syncthreads();
  float a0 = b_ed2[0], a1 = b_ed2[1], a2 = b_ed2[2];
  const float* zbrow = Zb + gd*HH;
  #pragma unroll 4
  for (int k = 0; k < HH; ++k) {
    float h = fmaxf(zt_s[k] + zbrow[k] + b1_s[k], 0.f);
    a0 = fmaf(h, w2_s[k*3 + 0], a0);
    a1 = fmaf(h, w2_s[k*3 + 1], a1);
    a2 = fmaf(h, w2_s[k*3 + 2], a2);
  }
  float* o = R + (gs*256 + gd)*3;
  o[0] = a0; o[1] = a1; o[2] = a2;
}

// K5': EXACT R11 k5 structure + k4 edge-gather fused as a per-thread tail
// (2 edges/thread, int2 loads, float2 stores; Rt ready because k3 ran first).
__global__ __launch_bounds__(512, 4) void k5_node(
    const float* __restrict__ node_emb, const __bf16* __restrict__ Bp,
    const __bf16* __restrict__ Bp2, const int* __restrict__ seg,
    const float* __restrict__ b_nep, const float* __restrict__ b_nd1,
    const float* __restrict__ W_nd2, const float* __restrict__ b_nd2,
    const float* __restrict__ ZN, float* __restrict__ out_node,
    const int* __restrict__ esrc, const int* __restrict__ edst,
    const float* __restrict__ Rt, float* __restrict__ out_edge)
{
  __shared__ __align__(16) char lds_raw[81920];
  __bf16* nep_s = (__bf16*)lds_raw;

  const int tid = threadIdx.x;
  const int w   = tid >> 6;
  const int l15 = tid & 15;
  const int g4  = (tid >> 4) & 3;
  const int wr  = w >> 1;
  const int wc  = w & 1;
  const int rowbase = blockIdx.x * 128;

  f32x4 acc[2][8];
  const f32x4 fzero = {0.f, 0.f, 0.f, 0.f};
  #pragma unroll
  for (int rt = 0; rt < 2; ++rt)
    #pragma unroll
    for (int ct = 0; ct < 8; ++ct) acc[rt][ct] = fzero;

  const int arow_t = tid >> 3;
  const int aoff   = (((tid & 7) ^ (arow_t & 7)) << 2);
  const int axor   = (l15 & 7) << 4;

  #define CVT8(DST, LO, HI)                                                     \
  { f32x4 lo_ = (LO), hi_ = (HI);                                               \
    DST[0]=(__bf16)lo_[0]; DST[1]=(__bf16)lo_[1]; DST[2]=(__bf16)lo_[2]; DST[3]=(__bf16)lo_[3]; \
    DST[4]=(__bf16)hi_[0]; DST[5]=(__bf16)hi_[1]; DST[6]=(__bf16)hi_[2]; DST[7]=(__bf16)hi_[3]; }

  #define STAGE_B(KB, BUF)                                                      \
  {                                                                             \
    int kb_ = (KB) > 31 ? 31 : (KB);                                            \
    char* Bd = lds_raw + 49152 + (BUF)*16384;                                   \
    const __bf16* bsrc = Bp + (size_t)kb_*8192 + tid*8;                         \
    gload_lds16(bsrc,        Bd + tid*16);                                      \
    gload_lds16(bsrc + 4096, Bd + tid*16 + 8192);                               \
  }

  #define STAGE_A(KB, BUF)                                                      \
  {                                                                             \
    int kb_ = (KB) > 31 ? 31 : (KB);                                            \
    char* Ad = lds_raw + (BUF)*16384;                                           \
    const float* asrc = node_emb + (size_t)rowbase*NEF + kb_*32 + aoff;         \
    gload_lds16(asrc + (size_t)arow_t*NEF,        Ad + tid*16);                 \
    gload_lds16(asrc + (size_t)(arow_t + 64)*NEF, Ad + tid*16 + 8192);          \
  }

  STAGE_B(0, 0);
  STAGE_A(0, 0);
  STAGE_A(1, 1);
  __builtin_amdgcn_sched_barrier(0);
  asm volatile("s_waitcnt vmcnt(2)" ::: "memory");
  __builtin_amdgcn_s_barrier();
  __builtin_amdgcn_sched_barrier(0);

  const int p0 = (((wr*32 + l15)*128)      + g4*32) ^ axor;
  const int p1 = (((wr*32 + 16 + l15)*128) + g4*32) ^ axor;

  int aR = 0;
  int aW = 2;

  #pragma unroll 2
  for (int kk = 0; kk < 32; ++kk) {
    const int c = kk & 1;
    STAGE_B(kk + 1, c ^ 1);
    STAGE_A(kk + 2, aW);
    __builtin_amdgcn_sched_barrier(0);
    const char* Ab = lds_raw + aR*16384;
    const char* Bb = lds_raw + 49152 + c*16384;
    f32x4 a00 = *(const f32x4*)(Ab + p0);
    f32x4 a01 = *(const f32x4*)(Ab + (p0 ^ 16));
    f32x4 a10 = *(const f32x4*)(Ab + p1);
    f32x4 a11 = *(const f32x4*)(Ab + (p1 ^ 16));
    bf16x8 aa0, aa1;
    CVT8(aa0, a00, a01);
    CVT8(aa1, a10, a11);
    const bf16x8* Bv = (const bf16x8*)Bb;
    #pragma unroll
    for (int ct = 0; ct < 8; ++ct) {
      bf16x8 bfr = Bv[g4*256 + wc*128 + ct*16 + l15];
      acc[0][ct] = __builtin_amdgcn_mfma_f32_16x16x32_bf16(aa0, bfr, acc[0][ct], 0, 0, 0);
      acc[1][ct] = __builtin_amdgcn_mfma_f32_16x16x32_bf16(aa1, bfr, acc[1][ct], 0, 0, 0);
    }
    __builtin_amdgcn_sched_barrier(0);
    asm volatile("s_waitcnt vmcnt(2)" ::: "memory");
    __builtin_amdgcn_s_barrier();
    __builtin_amdgcn_sched_barrier(0);
    aR = (aR == 2) ? 0 : aR + 1;
    aW = (aW == 2) ? 0 : aW + 1;
  }
  #undef STAGE_A
  #undef STAGE_B

  asm volatile("s_waitcnt vmcnt(0)" ::: "memory");
  __syncthreads();

  // epilogue 1: nep = relu(acc + b_nep) -> LDS (bf16)
  #pragma unroll
  for (int rt = 0; rt < 2; ++rt)
    #pragma unroll
    for (int ct = 0; ct < 8; ++ct) {
      int col = wc*128 + ct*16 + l15;
      float bn = b_nep[col];
      #pragma unroll
      for (int r = 0; r < 4; ++r) {
        float v = fmaxf(acc[rt][ct][r] + bn, 0.f);
        int row = wr*32 + rt*16 + g4*4 + r;
        nep_s[row*264 + col] = (__bf16)v;
      }
    }
  __syncthreads();

  // GEMM2
  f32x4 acc2[8];
  #pragma unroll
  for (int t = 0; t < 8; ++t) acc2[t] = fzero;
  const __bf16* nrow = nep_s + (w*16 + l15)*264 + g4*8;
  #pragma unroll 2
  for (int kk = 0; kk < 8; ++kk) {
    bf16x8 a2 = *(const bf16x8*)(nrow + kk*32);
    #pragma unroll
    for (int t = 0; t < 8; ++t) {
      bf16x8 b2 = *(const bf16x8*)(Bp2 + ((kk*4 + g4)*128 + t*16 + l15)*8);
      acc2[t] = __builtin_amdgcn_mfma_f32_16x16x32_bf16(a2, b2, acc2[t], 0, 0, 0);
    }
  }

  // epilogue 2
  int sid[4];
  #pragma unroll
  for (int r = 0; r < 4; ++r) sid[r] = seg[rowbase + w*16 + g4*4 + r];
  float p[4][4];
  #pragma unroll
  for (int r = 0; r < 4; ++r)
    #pragma unroll
    for (int c2 = 0; c2 < 4; ++c2) p[r][c2] = 0.f;
  #pragma unroll
  for (int t = 0; t < 8; ++t) {
    int col = t*16 + l15;
    float b1 = b_nd1[col];
    f32x4 w2 = *(const f32x4*)(W_nd2 + col*4);
    #pragma unroll
    for (int r = 0; r < 4; ++r) {
      float h = fmaxf(acc2[t][r] + ZN[sid[r]*HH + col] + b1, 0.f);
      p[r][0] = fmaf(h, w2[0], p[r][0]);
      p[r][1] = fmaf(h, w2[1], p[r][1]);
      p[r][2] = fmaf(h, w2[2], p[r][2]);
      p[r][3] = fmaf(h, w2[3], p[r][3]);
    }
  }
  #pragma unroll
  for (int off = 1; off < 16; off <<= 1)
    #pragma unroll
    for (int r = 0; r < 4; ++r)
      #pragma unroll
      for (int c2 = 0; c2 < 4; ++c2)
        p[r][c2] += __shfl_xor(p[r][c2], off, 64);
  if (l15 == 0) {
    f32x4 bn2 = *(const f32x4*)b_nd2;
    #pragma unroll
    for (int r = 0; r < 4; ++r) {
      f32x4 v = { p[r][0] + bn2[0], p[r][1] + bn2[1], p[r][2] + bn2[2], p[r][3] + bn2[3] };
      *(f32x4*)(out_node + (size_t)(rowbase + w*16 + g4*4 + r)*4) = v;
    }
  }

  // ---- fused k4 tail: 2 edges per thread (Rt produced by k3, launched earlier)
  {
    int gid = blockIdx.x*512 + tid;            // 262144 threads
    int2 s2 = ((const int2*)esrc)[gid];
    int2 d2 = ((const int2*)edst)[gid];
    int b0 = (seg[s2.x]*256 + seg[d2.x])*3;
    int b1 = (seg[s2.y]*256 + seg[d2.y])*3;
    float r00 = Rt[b0], r01 = Rt[b0+1], r02 = Rt[b0+2];
    float r10 = Rt[b1], r11 = Rt[b1+1], r12 = Rt[b1+2];
    float* o = out_edge + (size_t)gid*6;
    float2 v0 = { r00, r01 };
    float2 v1 = { r02, r10 };
    float2 v2 = { r11, r12 };
    *(float2*)(o)     = v0;
    *(float2*)(o + 2) = v1;
    *(float2*)(o + 4) = v2;
  }
  #undef CVT8
}

extern "C" void kernel_launch(void* const* d_in, const int* in_sizes, int n_in,
                              void* d_out, int out_size, void* d_ws, size_t ws_size,
                              hipStream_t stream) {
  const float* z        = (const float*)d_in[0];
  const float* node_emb = (const float*)d_in[1];
  const float* lattice  = (const float*)d_in[2];
  const int*   seg      = (const int*)d_in[3];
  const int*   src      = (const int*)d_in[4];
  const int*   dst      = (const int*)d_in[5];
  const float* W_lat    = (const float*)d_in[6];
  const float* b_lat    = (const float*)d_in[7];
  const float* W_nep    = (const float*)d_in[8];
  const float* b_nep    = (const float*)d_in[9];
  const float* W_nd1    = (const float*)d_in[10];
  const float* b_nd1    = (const float*)d_in[11];
  const float* W_nd2    = (const float*)d_in[12];
  const float* b_nd2    = (const float*)d_in[13];
  const float* W_ed1    = (const float*)d_in[14];
  const float* b_ed1    = (const float*)d_in[15];
  const float* W_ed2    = (const float*)d_in[16];
  const float* b_ed2    = (const float*)d_in[17];
  const float* W_en1    = (const float*)d_in[18];
  const float* b_en1    = (const float*)d_in[19];
  const float* W_en2    = (const float*)d_in[20];
  const float* b_en2    = (const float*)d_in[21];
  const float* W_st1    = (const float*)d_in[22];
  const float* b_st1    = (const float*)d_in[23];
  const float* W_st2    = (const float*)d_in[24];
  const float* b_st2    = (const float*)d_in[25];

  char* ws = (char*)d_ws;
  float*  Zt    = (float*)(ws + 0);          // 131072
  float*  Zb    = (float*)(ws + 131072);     // 131072
  float*  ZN    = (float*)(ws + 262144);     // 131072
  float*  Rt    = (float*)(ws + 393216);     // 786432
  __bf16* Bp    = (__bf16*)(ws + 1179648);   // 524288
  __bf16* Bp2   = (__bf16*)(ws + 1703936);   // 65536

  float* out_node = (float*)d_out;                 // 65536*4
  float* out_edge = out_node + 262144;             // 524288*3
  float* out_en   = out_node + 1835008;            // 256*2
  float* out_st   = out_node + 1835520;            // 256*9

  hipLaunchKernelGGL(k1_prep, dim3(912), dim3(256), 0, stream,
                     z, lattice, W_lat, b_lat, W_en1, b_en1, W_en2, b_en2,
                     W_st1, b_st1, W_st2, b_st2, W_nep, W_nd1, W_ed1,
                     Zt, Zb, ZN, Bp, Bp2, out_en, out_st);
  hipLaunchKernelGGL(k3_rtab, dim3(256), dim3(256), 0, stream,
                     Zt, Zb, b_ed1, W_ed2, b_ed2, Rt);
  hipLaunchKernelGGL(k5_node, dim3(512), dim3(512), 0, stream,
                     node_emb, Bp, Bp2, seg, b_nep, b_nd1, W_nd2, b_nd2, ZN, out_node,
                     src, dst, Rt, out_edge);
}

// Round 22
// 86.291 us; speedup vs baseline: 1.0093x; 1.0093x over previous
//
#include <hip/hip_runtime.h>
#include <hip/hip_bf16.h>

#define NN 65536
#define EE 524288
#define BB 256
#define LL 64
#define HH 128
#define DD2 256
#define NEF 1024

typedef __attribute__((ext_vector_type(4))) float f32x4;
typedef __attribute__((ext_vector_type(8))) __bf16 bf16x8;

__device__ __forceinline__ void gload_lds16(const void* g, void* l) {
  __builtin_amdgcn_global_load_lds(
      (__attribute__((address_space(1))) void*)(g),
      (__attribute__((address_space(3))) void*)(l), 16, 0, 0);
}

// K1 v2: latency-optimized z-path. 512 z-blocks (row b x role) + 144 conversion.
// role 0: Zt+ZN via split-K (2 groups x 128) with 2-acc ILP.
// role 1: Zb via split-K + heads (layer1 co-issued with zp; layer2 16-lane groups).
__global__ __launch_bounds__(256) void k1_prep(
    const float* __restrict__ z, const float* __restrict__ lattice,
    const float* __restrict__ W_lat, const float* __restrict__ b_lat,
    const float* __restrict__ W_en1, const float* __restrict__ b_en1,
    const float* __restrict__ W_en2, const float* __restrict__ b_en2,
    const float* __restrict__ W_st1, const float* __restrict__ b_st1,
    const float* __restrict__ W_st2, const float* __restrict__ b_st2,
    const float* __restrict__ W_nep, const float* __restrict__ W_nd1,
    const float* __restrict__ W_ed1,
    float* __restrict__ Zt, float* __restrict__ Zb, float* __restrict__ ZN,
    __bf16* __restrict__ Bp, __bf16* __restrict__ Bp2,
    float* __restrict__ out_en, float* __restrict__ out_st)
{
  int bid = blockIdx.x, t = threadIdx.x;
  if (bid < 2*BB) {
    int b = bid >> 1, role = bid & 1;
    __shared__ float zl[70];
    __shared__ float zp[DD2];
    __shared__ float redA[256];
    __shared__ float redN[256];
    __shared__ float hh[DD2];          // he (0..127) | hs (128..255), role 1 only

    if (t < LL) zl[t] = z[b*LL + t];
    else if (t < 70) zl[t] = lattice[t - LL];
    __syncthreads();

    // zp[t] with 2-acc ILP; role 1 co-issues head layer 1
    float p0 = b_lat[t], p1 = 0.f;
    #pragma unroll 8
    for (int k = 0; k < LL; k += 2) {
      p0 = fmaf(zl[k],   W_lat[k*DD2 + t],     p0);
      p1 = fmaf(zl[k+1], W_lat[(k+1)*DD2 + t], p1);
    }
    if (role) {
      const float* Wh = (t < HH) ? (W_en1 + t) : (W_st1 + (t - HH));
      float h0 = (t < HH) ? b_en1[t] : b_st1[t - HH];
      float h1 = 0.f;
      #pragma unroll 8
      for (int k = 0; k < 70; k += 2) {
        h0 = fmaf(zl[k],   Wh[(size_t)k*HH],     h0);
        h1 = fmaf(zl[k+1], Wh[(size_t)(k+1)*HH], h1);
      }
      hh[t] = fmaxf(h0 + h1, 0.f);
    }
    zp[t] = fmaxf(p0 + p1, 0.f);
    __syncthreads();

    int col = t & 127, kh = t >> 7;
    int k0 = kh * 128;
    if (role == 0) {
      const float* We = W_ed1 + col;
      const float* Wn = W_nd1 + col;
      float a0=0.f, a1=0.f, n0=0.f, n1=0.f;
      #pragma unroll 8
      for (int k = k0; k < k0 + 128; k += 2) {
        a0 = fmaf(zp[k],   We[(size_t)k*HH],     a0);
        n0 = fmaf(zp[k],   Wn[(size_t)k*HH],     n0);
        a1 = fmaf(zp[k+1], We[(size_t)(k+1)*HH], a1);
        n1 = fmaf(zp[k+1], Wn[(size_t)(k+1)*HH], n1);
      }
      redA[t] = a0 + a1;
      redN[t] = n0 + n1;
      __syncthreads();
      if (kh == 0) {
        Zt[b*HH + col] = redA[col] + redA[col + 128];
        ZN[b*HH + col] = redN[col] + redN[col + 128];
      }
    } else {
      const float* We = W_ed1 + (size_t)DD2*HH + col;
      float a0=0.f, a1=0.f;
      #pragma unroll 8
      for (int k = k0; k < k0 + 128; k += 2) {
        a0 = fmaf(zp[k],   We[(size_t)k*HH],     a0);
        a1 = fmaf(zp[k+1], We[(size_t)(k+1)*HH], a1);
      }
      redA[t] = a0 + a1;
      __syncthreads();
      if (kh == 0) Zb[b*HH + col] = redA[col] + redA[col + 128];
      // heads layer 2: 16-lane groups, 11 outputs
      int g = t >> 4, l = t & 15;
      if (g < 11) {
        float s = 0.f;
        if (g < 2) {
          #pragma unroll
          for (int q = 0; q < 8; ++q) {
            int k = l + q*16;
            s = fmaf(hh[k], W_en2[k*2 + g], s);
          }
        } else {
          int j = g - 2;
          #pragma unroll
          for (int q = 0; q < 8; ++q) {
            int k = l + q*16;
            s = fmaf(hh[128 + k], W_st2[k*9 + j], s);
          }
        }
        s += __shfl_xor(s, 1, 64);
        s += __shfl_xor(s, 2, 64);
        s += __shfl_xor(s, 4, 64);
        s += __shfl_xor(s, 8, 64);
        if (l == 0) {
          if (g < 2) out_en[b*2 + g] = s + b_en2[g];
          else       out_st[b*9 + (g - 2)] = s + b_st2[g - 2];
        }
      }
    }
  } else if (bid < 2*BB + 128) {       // W_nep (1024x256) -> Bp
    int kb = bid - 2*BB;
    int col = t;
    bf16x8 v;
    #pragma unroll
    for (int j = 0; j < 8; ++j)
      v[j] = (__bf16)W_nep[(kb*8 + j)*256 + col];
    *(bf16x8*)(Bp + (kb*256 + col)*8) = v;
  } else {                             // W_nd1 (256x128) -> Bp2
    int kb = (bid - 2*BB - 128)*2 + (t >> 7);
    int col = t & 127;
    bf16x8 v;
    #pragma unroll
    for (int j = 0; j < 8; ++j)
      v[j] = (__bf16)W_nd1[(kb*8 + j)*128 + col];
    *(bf16x8*)(Bp2 + (kb*128 + col)*8) = v;
  }
}

// K3: R[gs][gd][c] = relu(Zt[gs]+Zb[gd]+b_ed1) @ W_ed2 + b_ed2   (256x256x3 table)
__global__ __launch_bounds__(256) void k3_rtab(
    const float* __restrict__ Zt, const float* __restrict__ Zb,
    const float* __restrict__ b_ed1, const float* __restrict__ W_ed2,
    const float* __restrict__ b_ed2, float* __restrict__ R)
{
  __shared__ float zt_s[HH];
  __shared__ float b1_s[HH];
  __shared__ float w2_s[HH*3];
  int gs = blockIdx.x, gd = threadIdx.x;
  if (gd < HH) {
    zt_s[gd] = Zt[gs*HH + gd];
    b1_s[gd] = b_ed1[gd];
    w2_s[gd] = W_ed2[gd];
    w2_s[gd + HH] = W_ed2[gd + HH];
    w2_s[gd + 2*HH] = W_ed2[gd + 2*HH];
  }
  __syncthreads();
  float a0 = b_ed2[0], a1 = b_ed2[1], a2 = b_ed2[2];
  const float* zbrow = Zb + gd*HH;
  #pragma unroll 4
  for (int k = 0; k < HH; ++k) {
    float h = fmaxf(zt_s[k] + zbrow[k] + b1_s[k], 0.f);
    a0 = fmaf(h, w2_s[k*3 + 0], a0);
    a1 = fmaf(h, w2_s[k*3 + 1], a1);
    a2 = fmaf(h, w2_s[k*3 + 2], a2);
  }
  float* o = R + (gs*256 + gd)*3;
  o[0] = a0; o[1] = a1; o[2] = a2;
}

// K5': EXACT R11 k5 structure + k4 edge-gather fused as a per-thread tail
// (2 edges/thread, int2 loads, float2 stores; Rt ready because k3 ran first).
__global__ __launch_bounds__(512, 4) void k5_node(
    const float* __restrict__ node_emb, const __bf16* __restrict__ Bp,
    const __bf16* __restrict__ Bp2, const int* __restrict__ seg,
    const float* __restrict__ b_nep, const float* __restrict__ b_nd1,
    const float* __restrict__ W_nd2, const float* __restrict__ b_nd2,
    const float* __restrict__ ZN, float* __restrict__ out_node,
    const int* __restrict__ esrc, const int* __restrict__ edst,
    const float* __restrict__ Rt, float* __restrict__ out_edge)
{
  __shared__ __align__(16) char lds_raw[81920];
  __bf16* nep_s = (__bf16*)lds_raw;

  const int tid = threadIdx.x;
  const int w   = tid >> 6;
  const int l15 = tid & 15;
  const int g4  = (tid >> 4) & 3;
  const int wr  = w >> 1;
  const int wc  = w & 1;
  const int rowbase = blockIdx.x * 128;

  f32x4 acc[2][8];
  const f32x4 fzero = {0.f, 0.f, 0.f, 0.f};
  #pragma unroll
  for (int rt = 0; rt < 2; ++rt)
    #pragma unroll
    for (int ct = 0; ct < 8; ++ct) acc[rt][ct] = fzero;

  const int arow_t = tid >> 3;
  const int aoff   = (((tid & 7) ^ (arow_t & 7)) << 2);
  const int axor   = (l15 & 7) << 4;

  #define CVT8(DST, LO, HI)                                                     \
  { f32x4 lo_ = (LO), hi_ = (HI);                                               \
    DST[0]=(__bf16)lo_[0]; DST[1]=(__bf16)lo_[1]; DST[2]=(__bf16)lo_[2]; DST[3]=(__bf16)lo_[3]; \
    DST[4]=(__bf16)hi_[0]; DST[5]=(__bf16)hi_[1]; DST[6]=(__bf16)hi_[2]; DST[7]=(__bf16)hi_[3]; }

  #define STAGE_B(KB, BUF)                                                      \
  {                                                                             \
    int kb_ = (KB) > 31 ? 31 : (KB);                                            \
    char* Bd = lds_raw + 49152 + (BUF)*16384;                                   \
    const __bf16* bsrc = Bp + (size_t)kb_*8192 + tid*8;                         \
    gload_lds16(bsrc,        Bd + tid*16);                                      \
    gload_lds16(bsrc + 4096, Bd + tid*16 + 8192);                               \
  }

  #define STAGE_A(KB, BUF)                                                      \
  {                                                                             \
    int kb_ = (KB) > 31 ? 31 : (KB);                                            \
    char* Ad = lds_raw + (BUF)*16384;                                           \
    const float* asrc = node_emb + (size_t)rowbase*NEF + kb_*32 + aoff;         \
    gload_lds16(asrc + (size_t)arow_t*NEF,        Ad + tid*16);                 \
    gload_lds16(asrc + (size_t)(arow_t + 64)*NEF, Ad + tid*16 + 8192);          \
  }

  STAGE_B(0, 0);
  STAGE_A(0, 0);
  STAGE_A(1, 1);
  __builtin_amdgcn_sched_barrier(0);
  asm volatile("s_waitcnt vmcnt(2)" ::: "memory");
  __builtin_amdgcn_s_barrier();
  __builtin_amdgcn_sched_barrier(0);

  const int p0 = (((wr*32 + l15)*128)      + g4*32) ^ axor;
  const int p1 = (((wr*32 + 16 + l15)*128) + g4*32) ^ axor;

  int aR = 0;
  int aW = 2;

  #pragma unroll 2
  for (int kk = 0; kk < 32; ++kk) {
    const int c = kk & 1;
    STAGE_B(kk + 1, c ^ 1);
    STAGE_A(kk + 2, aW);
    __builtin_amdgcn_sched_barrier(0);
    const char* Ab = lds_raw + aR*16384;
    const char* Bb = lds_raw + 49152 + c*16384;
    f32x4 a00 = *(const f32x4*)(Ab + p0);
    f32x4 a01 = *(const f32x4*)(Ab + (p0 ^ 16));
    f32x4 a10 = *(const f32x4*)(Ab + p1);
    f32x4 a11 = *(const f32x4*)(Ab + (p1 ^ 16));
    bf16x8 aa0, aa1;
    CVT8(aa0, a00, a01);
    CVT8(aa1, a10, a11);
    const bf16x8* Bv = (const bf16x8*)Bb;
    #pragma unroll
    for (int ct = 0; ct < 8; ++ct) {
      bf16x8 bfr = Bv[g4*256 + wc*128 + ct*16 + l15];
      acc[0][ct] = __builtin_amdgcn_mfma_f32_16x16x32_bf16(aa0, bfr, acc[0][ct], 0, 0, 0);
      acc[1][ct] = __builtin_amdgcn_mfma_f32_16x16x32_bf16(aa1, bfr, acc[1][ct], 0, 0, 0);
    }
    __builtin_amdgcn_sched_barrier(0);
    asm volatile("s_waitcnt vmcnt(2)" ::: "memory");
    __builtin_amdgcn_s_barrier();
    __builtin_amdgcn_sched_barrier(0);
    aR = (aR == 2) ? 0 : aR + 1;
    aW = (aW == 2) ? 0 : aW + 1;
  }
  #undef STAGE_A
  #undef STAGE_B

  asm volatile("s_waitcnt vmcnt(0)" ::: "memory");
  __syncthreads();

  // epilogue 1: nep = relu(acc + b_nep) -> LDS (bf16)
  #pragma unroll
  for (int rt = 0; rt < 2; ++rt)
    #pragma unroll
    for (int ct = 0; ct < 8; ++ct) {
      int col = wc*128 + ct*16 + l15;
      float bn = b_nep[col];
      #pragma unroll
      for (int r = 0; r < 4; ++r) {
        float v = fmaxf(acc[rt][ct][r] + bn, 0.f);
        int row = wr*32 + rt*16 + g4*4 + r;
        nep_s[row*264 + col] = (__bf16)v;
      }
    }
  __syncthreads();

  // GEMM2
  f32x4 acc2[8];
  #pragma unroll
  for (int t = 0; t < 8; ++t) acc2[t] = fzero;
  const __bf16* nrow = nep_s + (w*16 + l15)*264 + g4*8;
  #pragma unroll 2
  for (int kk = 0; kk < 8; ++kk) {
    bf16x8 a2 = *(const bf16x8*)(nrow + kk*32);
    #pragma unroll
    for (int t = 0; t < 8; ++t) {
      bf16x8 b2 = *(const bf16x8*)(Bp2 + ((kk*4 + g4)*128 + t*16 + l15)*8);
      acc2[t] = __builtin_amdgcn_mfma_f32_16x16x32_bf16(a2, b2, acc2[t], 0, 0, 0);
    }
  }

  // epilogue 2
  int sid[4];
  #pragma unroll
  for (int r = 0; r < 4; ++r) sid[r] = seg[rowbase + w*16 + g4*4 + r];
  float p[4][4];
  #pragma unroll
  for (int r = 0; r < 4; ++r)
    #pragma unroll
    for (int c2 = 0; c2 < 4; ++c2) p[r][c2] = 0.f;
  #pragma unroll
  for (int t = 0; t < 8; ++t) {
    int col = t*16 + l15;
    float b1 = b_nd1[col];
    f32x4 w2 = *(const f32x4*)(W_nd2 + col*4);
    #pragma unroll
    for (int r = 0; r < 4; ++r) {
      float h = fmaxf(acc2[t][r] + ZN[sid[r]*HH + col] + b1, 0.f);
      p[r][0] = fmaf(h, w2[0], p[r][0]);
      p[r][1] = fmaf(h, w2[1], p[r][1]);
      p[r][2] = fmaf(h, w2[2], p[r][2]);
      p[r][3] = fmaf(h, w2[3], p[r][3]);
    }
  }
  #pragma unroll
  for (int off = 1; off < 16; off <<= 1)
    #pragma unroll
    for (int r = 0; r < 4; ++r)
      #pragma unroll
      for (int c2 = 0; c2 < 4; ++c2)
        p[r][c2] += __shfl_xor(p[r][c2], off, 64);
  if (l15 == 0) {
    f32x4 bn2 = *(const f32x4*)b_nd2;
    #pragma unroll
    for (int r = 0; r < 4; ++r) {
      f32x4 v = { p[r][0] + bn2[0], p[r][1] + bn2[1], p[r][2] + bn2[2], p[r][3] + bn2[3] };
      *(f32x4*)(out_node + (size_t)(rowbase + w*16 + g4*4 + r)*4) = v;
    }
  }

  // ---- fused k4 tail: 2 edges per thread (Rt produced by k3, launched earlier)
  {
    int gid = blockIdx.x*512 + tid;            // 262144 threads
    int2 s2 = ((const int2*)esrc)[gid];
    int2 d2 = ((const int2*)edst)[gid];
    int b0 = (seg[s2.x]*256 + seg[d2.x])*3;
    int b1 = (seg[s2.y]*256 + seg[d2.y])*3;
    float r00 = Rt[b0], r01 = Rt[b0+1], r02 = Rt[b0+2];
    float r10 = Rt[b1], r11 = Rt[b1+1], r12 = Rt[b1+2];
    float* o = out_edge + (size_t)gid*6;
    float2 v0 = { r00, r01 };
    float2 v1 = { r02, r10 };
    float2 v2 = { r11, r12 };
    *(float2*)(o)     = v0;
    *(float2*)(o + 2) = v1;
    *(float2*)(o + 4) = v2;
  }
  #undef CVT8
}

extern "C" void kernel_launch(void* const* d_in, const int* in_sizes, int n_in,
                              void* d_out, int out_size, void* d_ws, size_t ws_size,
                              hipStream_t stream) {
  const float* z        = (const float*)d_in[0];
  const float* node_emb = (const float*)d_in[1];
  const float* lattice  = (const float*)d_in[2];
  const int*   seg      = (const int*)d_in[3];
  const int*   src      = (const int*)d_in[4];
  const int*   dst      = (const int*)d_in[5];
  const float* W_lat    = (const float*)d_in[6];
  const float* b_lat    = (const float*)d_in[7];
  const float* W_nep    = (const float*)d_in[8];
  const float* b_nep    = (const float*)d_in[9];
  const float* W_nd1    = (const float*)d_in[10];
  const float* b_nd1    = (const float*)d_in[11];
  const float* W_nd2    = (const float*)d_in[12];
  const float* b_nd2    = (const float*)d_in[13];
  const float* W_ed1    = (const float*)d_in[14];
  const float* b_ed1    = (const float*)d_in[15];
  const float* W_ed2    = (const float*)d_in[16];
  const float* b_ed2    = (const float*)d_in[17];
  const float* W_en1    = (const float*)d_in[18];
  const float* b_en1    = (const float*)d_in[19];
  const float* W_en2    = (const float*)d_in[20];
  const float* b_en2    = (const float*)d_in[21];
  const float* W_st1    = (const float*)d_in[22];
  const float* b_st1    = (const float*)d_in[23];
  const float* W_st2    = (const float*)d_in[24];
  const float* b_st2    = (const float*)d_in[25];

  char* ws = (char*)d_ws;
  float*  Zt    = (float*)(ws + 0);          // 131072
  float*  Zb    = (float*)(ws + 131072);     // 131072
  float*  ZN    = (float*)(ws + 262144);     // 131072
  float*  Rt    = (float*)(ws + 393216);     // 786432
  __bf16* Bp    = (__bf16*)(ws + 1179648);   // 524288
  __bf16* Bp2   = (__bf16*)(ws + 1703936);   // 65536

  float* out_node = (float*)d_out;                 // 65536*4
  float* out_edge = out_node + 262144;             // 524288*3
  float* out_en   = out_node + 1835008;            // 256*2
  float* out_st   = out_node + 1835520;            // 256*9

  hipLaunchKernelGGL(k1_prep, dim3(656), dim3(256), 0, stream,
                     z, lattice, W_lat, b_lat, W_en1, b_en1, W_en2, b_en2,
                     W_st1, b_st1, W_st2, b_st2, W_nep, W_nd1, W_ed1,
                     Zt, Zb, ZN, Bp, Bp2, out_en, out_st);
  hipLaunchKernelGGL(k3_rtab, dim3(256), dim3(256), 0, stream,
                     Zt, Zb, b_ed1, W_ed2, b_ed2, Rt);
  hipLaunchKernelGGL(k5_node, dim3(512), dim3(512), 0, stream,
                     node_emb, Bp, Bp2, seg, b_nep, b_nd1, W_nd2, b_nd2, ZN, out_node,
                     src, dst, Rt, out_edge);
}